// Round 5
// baseline (316.976 us; speedup 1.0000x reference)
//
#include <hip/hip_runtime.h>
#include <hip/hip_bf16.h>

// B=16, S=2048, D=128 causal attention, pre-scale threshold:
//   A = Q@T^T; A = (A>0.3 ? A : 0); causal -2^32; /sqrt(128); softmax; @V
// fp32 in/out, bf16 MFMA internal. Fixed-max softmax (m=0; post-threshold
// logits in [0,~9]) => partial (oacc, sum-l) accumulators are ADDITIVE.
//
// V6 = V4's proven per-wave compute body (88 VGPR, 16x16x32 MFMA, P via
// per-wave LDS scratch) with one structural change: 8-wave blocks covering
// 128 q-rows per tile (vs 4-wave/64).
//  * tile-slots per CU halve (33->17); DMA bytes, vmcnt waits, barriers halve
//    per unit work.
//  * __launch_bounds__(512,4): VGPR cap 128 >= body's 88 (V3's spill came
//    from a 64-cap; this is safe) => 2 blocks/CU x 8 waves = 4 waves/SIMD,
//    double V4's TLP. LDS 80KB x 2 = 160KB exactly fits.
//  * nrm kernel folded into fa via chunk-static partial slots + spin
//    finalizer (V5's proven protocol; slots fixed per chunk => no tickets).
// Work split: pairs (pi,15-pi) of 128-row q-tiles, 34 key-tiles per pair,
// light-first enumeration chunked [0,9,17,26,34) over 4 blocks.

#define S_LEN 2048
#define D_DIM 128
#define THRESH 0.3f
#define SCALE 0.08838834764831845f   // 1/sqrt(128)

typedef __bf16 bf16x8 __attribute__((ext_vector_type(8)));
typedef float f32x4 __attribute__((ext_vector_type(4)));

#define GLD16(g, l)                                                         \
    __builtin_amdgcn_global_load_lds(                                       \
        (const __attribute__((address_space(1))) unsigned int*)(g),         \
        (__attribute__((address_space(3))) unsigned int*)(l), 16, 0, 0)

// ---- prep: Tb bf16 downcast; Vt[b][d][s] bf16 transpose; zero done ctrs ----
__global__ void prep_kernel(const float* __restrict__ V, const float* __restrict__ T,
                            __bf16* __restrict__ Vt, __bf16* __restrict__ Tb,
                            int* __restrict__ done) {
    __shared__ float tile[64][65];
    int bid = blockIdx.x;                      // 1024 blocks
    int tid = threadIdx.x;                     // 256 threads
    if (bid == 0) done[tid] = 0;
    int b  = bid >> 6;
    int t2 = bid & 63;

    {   // T downcast: rows [t2*32, t2*32+32) of batch b; 16 f32 per thread
        int flat = tid * 16;
        int r = flat >> 7, cc = flat & 127;
        const float* p = T + ((size_t)b * S_LEN + t2 * 32 + r) * D_DIM + cc;
        __bf16* q = Tb + ((size_t)b * S_LEN + t2 * 32 + r) * D_DIM + cc;
        bf16x8 w0, w1;
        f32x4 a0 = *(const f32x4*)p,       a1 = *(const f32x4*)(p + 4);
        f32x4 a2 = *(const f32x4*)(p + 8), a3 = *(const f32x4*)(p + 12);
        #pragma unroll
        for (int j = 0; j < 4; ++j) {
            w0[j] = (__bf16)a0[j]; w0[4 + j] = (__bf16)a1[j];
            w1[j] = (__bf16)a2[j]; w1[4 + j] = (__bf16)a3[j];
        }
        *(bf16x8*)q = w0;
        *(bf16x8*)(q + 8) = w1;
    }

    int s0 = (t2 >> 1) * 64;
    int d0 = (t2 & 1) * 64;
    #pragma unroll
    for (int it = 0; it < 2; ++it) {
        int row = it * 32 + (tid >> 3);
        int c   = (tid & 7) * 8;
        const float* p = V + ((size_t)b * S_LEN + s0 + row) * D_DIM + d0 + c;
        *(f32x4*)(&tile[row][c])     = *(const f32x4*)p;
        *(f32x4*)(&tile[row][c + 4]) = *(const f32x4*)(p + 4);
    }
    __syncthreads();
    #pragma unroll
    for (int it = 0; it < 2; ++it) {
        int dr = it * 32 + (tid >> 3);
        int c  = (tid & 7) * 8;
        bf16x8 w;
        #pragma unroll
        for (int j = 0; j < 8; ++j) w[j] = (__bf16)tile[c + j][dr];
        *(bf16x8*)(Vt + ((size_t)b * D_DIM + d0 + dr) * S_LEN + s0 + c) = w;
    }
}

// ---------------- Flash attention, causal + threshold, fixed-max ----------------
// 512 threads = 8 waves; each wave owns 16 q-rows of a 128-row q-tile.
// LDS 81920 B (2 blocks/CU = 160KB exactly):
//   [    0, 32768)  Tt dbuf: 2 x (64 rows x 256B), XOR-swizzled via DMA source
//   [32768, 65536)  Vl dbuf: 2 x (128 rows x 128B), XOR-swizzled via DMA source
//   [65536, 81920)  Pl: 8 waves x 2KB (16 rows x 128B, swizzled)
__global__ __launch_bounds__(512, 4)
void fa_kernel(const float* __restrict__ Q, const __bf16* __restrict__ Tb,
               const __bf16* __restrict__ Vt, float* __restrict__ O,
               __bf16* __restrict__ pO, float* __restrict__ pL,
               int* __restrict__ done) {
    __shared__ __align__(16) unsigned char smem[81920];

    const int bid = blockIdx.x;          // 512 = b(4b) | pair(3b) | chunk(2b)
    const int b   = bid & 15;
    const int pi  = (bid >> 4) & 7;      // pair: q-tiles (pi, 15-pi), 128 rows each
    const int c   = bid >> 7;            // chunk 0..3 of [0,9,17,26,34)
    const int L2  = 2 * pi + 2;          // light k-tile count (2..16)
    const int pr  = b * 8 + pi;          // pair id 0..127
    const int qtL = pi, qtH = 15 - pi;

    const int tid  = threadIdx.x;
    const int lane = tid & 63;
    const int wv   = tid >> 6;           // wave 0..7
    const int col  = lane & 15;
    const int quad = lane >> 4;

    unsigned char* Pw = smem + 65536 + wv * 2048;
    const __bf16* TbB = Tb + (size_t)b * (S_LEN * D_DIM);
    const __bf16* VtB = Vt + (size_t)b * (D_DIM * S_LEN);

    // per-thread pre-swizzled global source offsets; 2 T + 2 V DMA per wave
    int toff[2], voff[2];
    #pragma unroll
    for (int i = 0; i < 2; ++i) {
        int trw = wv * 8 + i * 4 + (lane >> 4);
        toff[i] = trw * 128 + (((lane & 15) ^ (trw & 7)) << 3);
        int drw = wv * 16 + i * 8 + (lane >> 3);
        voff[i] = drw * 2048 + (((lane & 7) ^ (drw & 7)) << 3);
    }

    auto issueTile = [&](int k0, int buf) {
        const __bf16* ts = TbB + (size_t)k0 * D_DIM;
        const __bf16* vs = VtB + k0;
        unsigned char* lt = smem + buf * 16384 + wv * 2048;
        unsigned char* lv = smem + 32768 + buf * 16384 + wv * 2048;
        GLD16(ts + toff[0], lt);
        GLD16(ts + toff[1], lt + 1024);
        GLD16(vs + voff[0], lv);
        GLD16(vs + voff[1], lv + 1024);
    };

    bf16x8 qf[4];
    auto loadQ = [&](int jq) {
        const float* qptr = Q + ((size_t)b * S_LEN + jq * 128 + wv * 16 + col) * D_DIM + quad * 8;
        #pragma unroll
        for (int kk = 0; kk < 4; ++kk) {
            f32x4 a = *(const f32x4*)(qptr + kk * 32);
            f32x4 d = *(const f32x4*)(qptr + kk * 32 + 4);
            #pragma unroll
            for (int j = 0; j < 4; ++j) { qf[kk][j] = (__bf16)a[j]; qf[kk][4 + j] = (__bf16)d[j]; }
        }
    };

    f32x4 oacc[8];
    float lsum[4];

    auto computeTile = [&](int buf, int dK) {
        unsigned char* Tt = smem + buf * 16384;
        unsigned char* Vl = smem + 32768 + buf * 16384;
        f32x4 sacc[4];
        __builtin_amdgcn_s_setprio(1);
        #pragma unroll
        for (int t = 0; t < 4; ++t) {
            sacc[t] = {0.f, 0.f, 0.f, 0.f};
            #pragma unroll
            for (int kk = 0; kk < 4; ++kk) {
                int row = t * 16 + col;
                bf16x8 bf = *(const bf16x8*)(Tt + row * 256 + ((kk * 64 + quad * 16) ^ ((row & 7) << 4)));
                sacc[t] = __builtin_amdgcn_mfma_f32_16x16x32_bf16(qf[kk], bf, sacc[t], 0, 0, 0);
            }
        }
        __builtin_amdgcn_s_setprio(0);
        float p[4][4];
        #pragma unroll
        for (int t = 0; t < 4; ++t)
            #pragma unroll
            for (int r = 0; r < 4; ++r) {
                float s = sacc[t][r];
                float e = __expf(s * SCALE);
                p[t][r] = (s > THRESH) ? e : 1.0f;
            }
        if (dK < 64) {                       // partially-causal tiles (dK = 0 or -64)
            #pragma unroll
            for (int t = 0; t < 4; ++t)
                #pragma unroll
                for (int r = 0; r < 4; ++r)
                    if (t * 16 + col - (wv * 16 + quad * 4 + r) > dK) p[t][r] = 0.0f;
        }
        #pragma unroll
        for (int r = 0; r < 4; ++r)
            lsum[r] += (p[0][r] + p[1][r]) + (p[2][r] + p[3][r]);

        // C-layout -> LDS -> A-layout (per-wave scratch, swizzled)
        #pragma unroll
        for (int t = 0; t < 4; ++t)
            #pragma unroll
            for (int r = 0; r < 4; ++r) {
                int row = quad * 4 + r;
                *(__bf16*)(Pw + row * 128 + (((t * 16 + col) * 2) ^ ((row & 7) << 4))) = (__bf16)p[t][r];
            }
        asm volatile("s_waitcnt lgkmcnt(0)" ::: "memory");  // wave-local RAW on Pw

        __builtin_amdgcn_s_setprio(1);
        #pragma unroll
        for (int ks = 0; ks < 2; ++ks) {
            bf16x8 af = *(const bf16x8*)(Pw + col * 128 + ((ks * 64 + quad * 16) ^ ((col & 7) << 4)));
            #pragma unroll
            for (int dt = 0; dt < 8; ++dt) {
                int row = dt * 16 + col;
                bf16x8 bf = *(const bf16x8*)(Vl + row * 128 + ((ks * 64 + quad * 16) ^ ((row & 7) << 4)));
                oacc[dt] = __builtin_amdgcn_mfma_f32_16x16x32_bf16(af, bf, oacc[dt], 0, 0, 0);
            }
        }
        __builtin_amdgcn_s_setprio(0);
    };

    auto runSeg = [&](int jq, int k0t, int nt) {
        loadQ(jq);
        #pragma unroll
        for (int dt = 0; dt < 8; ++dt) oacc[dt] = {0.f, 0.f, 0.f, 0.f};
        #pragma unroll
        for (int r = 0; r < 4; ++r) lsum[r] = 0.f;
        issueTile(k0t * 64, 0);
        for (int s = 0; s < nt; ++s) {
            if (s + 1 < nt) {
                issueTile((k0t + s + 1) * 64, (s + 1) & 1);
                asm volatile("s_waitcnt vmcnt(4)" ::: "memory");  // tile s landed; s+1 in flight
            } else {
                asm volatile("s_waitcnt vmcnt(0)" ::: "memory");
            }
            __builtin_amdgcn_s_barrier();
            computeTile(s & 1, 128 * jq - 64 * (k0t + s));
            __builtin_amdgcn_s_barrier();
        }
    };

    float lred[4];
    auto reduceL = [&]() {
        #pragma unroll
        for (int r = 0; r < 4; ++r) {
            float l = lsum[r];
            l += __shfl_xor(l, 1); l += __shfl_xor(l, 2);
            l += __shfl_xor(l, 4); l += __shfl_xor(l, 8);
            lred[r] = l;
        }
    };

    auto storeO = [&](int jq) {
        float* optr = O + ((size_t)b * S_LEN + jq * 128 + wv * 16) * D_DIM;
        #pragma unroll
        for (int r = 0; r < 4; ++r) {
            float inv = 1.0f / lred[r];
            #pragma unroll
            for (int dt = 0; dt < 8; ++dt)
                optr[(quad * 4 + r) * D_DIM + dt * 16 + col] = oacc[dt][r] * inv;
        }
    };

    auto storePartial = [&](int slot, int* dcnt) {
        __bf16* po = pO + (size_t)(pr * 4 + slot) * (128 * 128);
        float*  pl = pL + (size_t)(pr * 4 + slot) * 128;
        #pragma unroll
        for (int dt = 0; dt < 8; ++dt)
            #pragma unroll
            for (int r = 0; r < 4; ++r)
                po[(wv * 16 + quad * 4 + r) * 128 + dt * 16 + col] = (__bf16)oacc[dt][r];
        if (col == 0) {
            #pragma unroll
            for (int r = 0; r < 4; ++r) pl[wv * 16 + quad * 4 + r] = lred[r];
        }
        __threadfence();
        __syncthreads();
        if (tid == 0)
            __hip_atomic_fetch_add(dcnt, 1, __ATOMIC_RELEASE, __HIP_MEMORY_SCOPE_AGENT);
    };

    auto addPartial = [&](int slot) {
        const __bf16* po = pO + (size_t)(pr * 4 + slot) * (128 * 128);
        const float*  pl = pL + (size_t)(pr * 4 + slot) * 128;
        #pragma unroll
        for (int dt = 0; dt < 8; ++dt)
            #pragma unroll
            for (int r = 0; r < 4; ++r)
                oacc[dt][r] += (float)po[(wv * 16 + quad * 4 + r) * 128 + dt * 16 + col];
        #pragma unroll
        for (int r = 0; r < 4; ++r) lred[r] += pl[wv * 16 + quad * 4 + r];
    };

    auto spinFor = [&](int* dcnt, int need) {
        if (tid == 0) {
            while (__hip_atomic_load(dcnt, __ATOMIC_ACQUIRE, __HIP_MEMORY_SCOPE_AGENT) < need)
                __builtin_amdgcn_s_sleep(8);
        }
        __syncthreads();
        __threadfence();
    };

    // ---- chunk schedule over the 34-tile pair enumeration [0,9,17,26,34) ----
    if (c == 0) {
        if (pi <= 3) {                               // L2 <= 8: light completes here
            runSeg(qtL, 0, L2);
            reduceL();
            storeO(qtL);
            runSeg(qtH, 0, 9 - L2);                  // heavy prefix (>=1 tile)
            reduceL();
            storePartial(0, &done[128 + pr]);
        } else {                                     // light part 1 of 2
            runSeg(qtL, 0, 9);
            reduceL();
            storePartial(3, &done[pr]);
        }
    } else if (c == 1) {
        if (pi <= 3) {
            runSeg(qtH, 9 - L2, 8);
            reduceL();
            storePartial(1, &done[128 + pr]);
        } else {
            runSeg(qtH, 0, 17 - L2);                 // heavy first (lets c0 finish light p1)
            reduceL();
            storePartial(1, &done[128 + pr]);
            runSeg(qtL, 9, L2 - 9);                  // light part 2 + finalize
            reduceL();
            spinFor(&done[pr], 1);
            addPartial(3);
            storeO(qtL);
        }
    } else if (c == 2) {
        runSeg(qtH, 17 - L2, 9);
        reduceL();
        storePartial(2, &done[128 + pr]);
    } else {
        runSeg(qtH, 26 - L2, 8);                     // heavy tail incl. diagonal
        reduceL();
        int s0 = (pi <= 3) ? 0 : 1;
        spinFor(&done[128 + pr], 3 - s0);
        for (int s = s0; s < 3; ++s) addPartial(s);
        storeO(qtH);
    }
}

extern "C" void kernel_launch(void* const* d_in, const int* in_sizes, int n_in,
                              void* d_out, int out_size, void* d_ws, size_t ws_size,
                              hipStream_t stream) {
    const float* Q = (const float*)d_in[0];
    const float* T = (const float*)d_in[1];
    const float* V = (const float*)d_in[2];
    float* O = (float*)d_out;

    // ws: Vt 8MB | Tb 8MB | pO 16MB bf16 (128 pairs x 4 slots x 128x128)
    //   | pL 256KB | done 1KB   (~32.3MB)
    unsigned char* ws = (unsigned char*)d_ws;
    __bf16* Vt = (__bf16*)ws;
    __bf16* Tb = (__bf16*)(ws + 8388608);
    __bf16* pO = (__bf16*)(ws + 16777216);
    float*  pL = (float*)(ws + 16777216 + 16777216);
    int*  done = (int*)(ws + 16777216 + 16777216 + 262144);

    prep_kernel<<<1024, 256, 0, stream>>>(V, T, Vt, Tb, done);
    fa_kernel<<<512, 512, 0, stream>>>(Q, Tb, Vt, O, pO, pL, done);
}

// Round 7
// 131.378 us; speedup vs baseline: 2.4127x; 2.4127x over previous
//
#include <hip/hip_runtime.h>
#include <hip/hip_bf16.h>

// B=16, S=2048, D=128 causal attention, pre-scale threshold:
//   A = Q@T^T; A = (A>0.3 ? A : 0); causal -2^32; /sqrt(128); softmax; @V
// fp32 in/out, bf16 MFMA internal. Fixed-max softmax (m=0; post-threshold
// logits in [0,~9]) => partial (oacc, sum-l) accumulators are ADDITIVE.
//
// V7 = V4 (best verified: fa 46.8us) with ONE change: work repartition inside
// the slot so per-wave LDS traffic drops 34r+16w -> 16r+4w ds-ops:
//  * QK^T key-split: wave w owns keys [16w,16w+16) x all 64 q. Q lives in
//    registers as 16 B-frags (qf[4][4], 64 VGPR); T is the A-frag => only
//    4 T-tile ds_read_b128 per wave (was 16; no 4x duplication across waves).
//  * PV d-split: wave w owns d in [32w,32w+32) x all 64 q => 4 V-tile reads
//    (was 16). P crosses waves via ONE shared 8KB [64q][64key] buffer:
//    4x ds_write_b64 (key axis is the C-layout r index => contiguous pack),
//    8x ds_read_b128 for A-frags. Costs one extra barrier per slot.
//  * l-sum now needs a cross-wave reduce ONCE PER SEGMENT (not per slot),
//    through 1KB of the P region (Lx[4][64]).
// Everything else is V4 verbatim: 2 waves/SIMD (V3+V6 proved 4 w/SIMD => cap
// 128 => spill disaster; launch_bounds(256,2) keeps cap 256), global_load_lds
// staging with pre-swizzled source, dbuf + counted vmcnt(8), grid 512 =
// (b, pair, chunk0/1), separate nrm kernel for the 2-contributor heavy tiles.
//
// R6 note: previous submission failed with "MI355X container failed twice"
// (broker infra, no compile/run evidence). V7 has no device-side spin loops
// and audited-in-bounds DMA/LDS addressing => resubmitted unchanged.

#define S_LEN 2048
#define D_DIM 128
#define THRESH 0.3f
#define SCALE 0.08838834764831845f   // 1/sqrt(128)

typedef __bf16 bf16x8 __attribute__((ext_vector_type(8)));
typedef __bf16 bf16x4 __attribute__((ext_vector_type(4)));
typedef float f32x4 __attribute__((ext_vector_type(4)));

#define GLD16(g, l)                                                         \
    __builtin_amdgcn_global_load_lds(                                       \
        (const __attribute__((address_space(1))) unsigned int*)(g),         \
        (__attribute__((address_space(3))) unsigned int*)(l), 16, 0, 0)

// ---- prep: Tb bf16 downcast; Vt[b][d][s] bf16 transpose ----
__global__ void prep_kernel(const float* __restrict__ V, const float* __restrict__ T,
                            __bf16* __restrict__ Vt, __bf16* __restrict__ Tb) {
    __shared__ float tile[64][65];
    int bid = blockIdx.x;                      // 1024 blocks
    int tid = threadIdx.x;                     // 256 threads
    int b  = bid >> 6;
    int t2 = bid & 63;

    {   // T downcast: rows [t2*32, t2*32+32) of batch b; 16 f32 per thread
        int flat = tid * 16;
        int r = flat >> 7, cc = flat & 127;
        const float* p = T + ((size_t)b * S_LEN + t2 * 32 + r) * D_DIM + cc;
        __bf16* q = Tb + ((size_t)b * S_LEN + t2 * 32 + r) * D_DIM + cc;
        bf16x8 w0, w1;
        f32x4 a0 = *(const f32x4*)p,       a1 = *(const f32x4*)(p + 4);
        f32x4 a2 = *(const f32x4*)(p + 8), a3 = *(const f32x4*)(p + 12);
        #pragma unroll
        for (int j = 0; j < 4; ++j) {
            w0[j] = (__bf16)a0[j]; w0[4 + j] = (__bf16)a1[j];
            w1[j] = (__bf16)a2[j]; w1[4 + j] = (__bf16)a3[j];
        }
        *(bf16x8*)q = w0;
        *(bf16x8*)(q + 8) = w1;
    }

    int s0 = (t2 >> 1) * 64;
    int d0 = (t2 & 1) * 64;
    #pragma unroll
    for (int it = 0; it < 2; ++it) {
        int row = it * 32 + (tid >> 3);
        int c   = (tid & 7) * 8;
        const float* p = V + ((size_t)b * S_LEN + s0 + row) * D_DIM + d0 + c;
        *(f32x4*)(&tile[row][c])     = *(const f32x4*)p;
        *(f32x4*)(&tile[row][c + 4]) = *(const f32x4*)(p + 4);
    }
    __syncthreads();
    #pragma unroll
    for (int it = 0; it < 2; ++it) {
        int dr = it * 32 + (tid >> 3);
        int c  = (tid & 7) * 8;
        bf16x8 w;
        #pragma unroll
        for (int j = 0; j < 8; ++j) w[j] = (__bf16)tile[c + j][dr];
        *(bf16x8*)(Vt + ((size_t)b * D_DIM + d0 + dr) * S_LEN + s0 + c) = w;
    }
}

// ---------------- Flash attention, causal + threshold, fixed-max ----------------
// 256 threads = 4 waves. LDS 73728 B => 2 blocks/CU:
//   [    0, 32768)  Tt dbuf: 2 x (64 rows x 256B), XOR-swizzled via DMA source
//   [32768, 65536)  Vl dbuf: 2 x (128 rows x 128B), XOR-swizzled via DMA source
//   [65536, 73728)  P: shared [64 q][128B keys] swizzled; first 1KB doubles as
//                   Lx[4][64] cross-wave l-reduction buffer between segments.
__global__ __launch_bounds__(256, 2)
void fa_kernel(const float* __restrict__ Q, const __bf16* __restrict__ Tb,
               const __bf16* __restrict__ Vt, float* __restrict__ O,
               float* __restrict__ pO, float* __restrict__ pL) {
    __shared__ __align__(16) unsigned char smem[73728];

    const int bid = blockIdx.x;          // 512: b fastest
    const int b   = bid & 15;
    const int pi  = (bid >> 4) & 15;     // pair index
    const int c   = bid >> 8;            // chunk 0/1
    const int qtH = 31 - pi;
    const int L   = pi + 1;              // light tile count (1..16)

    const int tid  = threadIdx.x;
    const int lane = tid & 63;
    const int wv   = tid >> 6;
    const int col  = lane & 15;
    const int quad = lane >> 4;

    unsigned char* Pb = smem + 65536;
    float* Lxf = (float*)(smem + 65536);

    const __bf16* TbB = Tb + (size_t)b * (S_LEN * D_DIM);
    const __bf16* VtB = Vt + (size_t)b * (D_DIM * S_LEN);

    // per-thread pre-swizzled global source offsets for the 4+4 DMA issues
    int toff[4], voff[4];
    #pragma unroll
    for (int i = 0; i < 4; ++i) {
        int trw = wv * 16 + i * 4 + (lane >> 4);
        toff[i] = trw * 128 + (((lane & 15) ^ (trw & 7)) << 3);
        int drw = wv * 32 + i * 8 + (lane >> 3);
        voff[i] = drw * 2048 + (((lane & 7) ^ (drw & 7)) << 3);
    }

    auto issueTile = [&](int k0, int buf) {
        const __bf16* ts = TbB + (size_t)k0 * D_DIM;
        const __bf16* vs = VtB + k0;
        unsigned char* lt = smem + buf * 16384 + wv * 4096;
        unsigned char* lv = smem + 32768 + buf * 16384 + wv * 4096;
        #pragma unroll
        for (int i = 0; i < 4; ++i) GLD16(ts + toff[i], lt + i * 1024);
        #pragma unroll
        for (int i = 0; i < 4; ++i) GLD16(vs + voff[i], lv + i * 1024);
    };

    // Q as PERSISTENT B-frags for all 64 q-rows: qf[t][kk] holds
    // Q[q = 16t+col][k = kk*32 + quad*8 + j]   (64 VGPRs)
    bf16x8 qf[4][4];
    auto loadQ = [&](int jq) {
        #pragma unroll
        for (int t = 0; t < 4; ++t) {
            const float* qptr = Q + ((size_t)b * S_LEN + jq * 64 + 16 * t + col) * D_DIM + quad * 8;
            #pragma unroll
            for (int kk = 0; kk < 4; ++kk) {
                f32x4 a = *(const f32x4*)(qptr + kk * 32);
                f32x4 d = *(const f32x4*)(qptr + kk * 32 + 4);
                #pragma unroll
                for (int j = 0; j < 4; ++j) { qf[t][kk][j] = (__bf16)a[j]; qf[t][kk][4 + j] = (__bf16)d[j]; }
            }
        }
    };

    f32x4 oacc[4][2];     // [t][dn][r]: q = 16t+quad*4+r, d = 32wv+16dn+col
    float lsum[4];        // per-lane l partial for q = 16t+col (this wave's keys)
    float lfull[4][4];    // after finishSeg: full l for q = 16t+quad*4+r

    auto computeTile = [&](int buf, bool diag) {
        unsigned char* Tt = smem + buf * 16384;
        unsigned char* Vl = smem + 32768 + buf * 16384;

        // ---- S-phase: wave's 16 keys x all 64 q.  A = T-frag, B = qf. ----
        f32x4 sacc[4];
        #pragma unroll
        for (int t = 0; t < 4; ++t) sacc[t] = {0.f, 0.f, 0.f, 0.f};
        __builtin_amdgcn_s_setprio(1);
        #pragma unroll
        for (int kk = 0; kk < 4; ++kk) {
            int trow = wv * 16 + col;      // key = 16wv + col  (A-frag m=col)
            bf16x8 tf = *(const bf16x8*)(Tt + trow * 256 + ((kk * 64 + quad * 16) ^ ((trow & 7) << 4)));
            #pragma unroll
            for (int t = 0; t < 4; ++t)
                sacc[t] = __builtin_amdgcn_mfma_f32_16x16x32_bf16(tf, qf[t][kk], sacc[t], 0, 0, 0);
        }
        __builtin_amdgcn_s_setprio(0);

        // D[m = key = quad*4+r (+16wv)][n = q = col (+16t)]
        float p[4][4];
        #pragma unroll
        for (int t = 0; t < 4; ++t)
            #pragma unroll
            for (int r = 0; r < 4; ++r) {
                float s = sacc[t][r];
                float e = __expf(s * SCALE);
                p[t][r] = (s > THRESH) ? e : 1.0f;
            }
        if (diag) {
            #pragma unroll
            for (int t = 0; t < 4; ++t)
                #pragma unroll
                for (int r = 0; r < 4; ++r)
                    if (wv * 16 + quad * 4 + r > 16 * t + col) p[t][r] = 0.0f;
        }
        #pragma unroll
        for (int t = 0; t < 4; ++t)
            lsum[t] += (p[t][0] + p[t][1]) + (p[t][2] + p[t][3]);

        // P[q][key]: key axis = r => 4 contiguous bf16 = one ds_write_b64
        #pragma unroll
        for (int t = 0; t < 4; ++t) {
            int row = 16 * t + col;
            bf16x4 w = {(__bf16)p[t][0], (__bf16)p[t][1], (__bf16)p[t][2], (__bf16)p[t][3]};
            *(bf16x4*)(Pb + row * 128 + ((32 * wv + 8 * quad) ^ ((row & 7) << 4))) = w;
        }
        asm volatile("s_waitcnt lgkmcnt(0)" ::: "memory");  // P writes drained
        __builtin_amdgcn_s_barrier();                       // b2: P visible

        // ---- PV: wave's 32 d-cols x all 64 q.  A = P-frag, B = V-frag. ----
        __builtin_amdgcn_s_setprio(1);
        #pragma unroll
        for (int kb = 0; kb < 2; ++kb) {
            bf16x8 pf[4];
            #pragma unroll
            for (int t = 0; t < 4; ++t) {
                int prow = 16 * t + col;
                pf[t] = *(const bf16x8*)(Pb + prow * 128 + ((kb * 64 + quad * 16) ^ ((prow & 7) << 4)));
            }
            #pragma unroll
            for (int dn = 0; dn < 2; ++dn) {
                int vrow = 32 * wv + 16 * dn + col;
                bf16x8 vf = *(const bf16x8*)(Vl + vrow * 128 + ((kb * 64 + quad * 16) ^ ((vrow & 7) << 4)));
                #pragma unroll
                for (int t = 0; t < 4; ++t)
                    oacc[t][dn] = __builtin_amdgcn_mfma_f32_16x16x32_bf16(pf[t], vf, oacc[t][dn], 0, 0, 0);
            }
        }
        __builtin_amdgcn_s_setprio(0);
    };

    auto runSeg = [&](int jq, int k0t, int nt) {
        loadQ(jq);
        #pragma unroll
        for (int t = 0; t < 4; ++t) {
            oacc[t][0] = {0.f, 0.f, 0.f, 0.f};
            oacc[t][1] = {0.f, 0.f, 0.f, 0.f};
            lsum[t] = 0.f;
        }
        issueTile(k0t * 64, 0);
        for (int s = 0; s < nt; ++s) {
            if (s + 1 < nt) {
                issueTile((k0t + s + 1) * 64, (s + 1) & 1);
                asm volatile("s_waitcnt vmcnt(8)" ::: "memory");  // tile s landed; s+1 in flight
            } else {
                asm volatile("s_waitcnt vmcnt(0)" ::: "memory");
            }
            __builtin_amdgcn_s_barrier();                         // b1: tile staged
            computeTile(s & 1, k0t + s == jq);
            __builtin_amdgcn_s_barrier();                         // b3: slot done
        }
    };

    // cross-wave l reduction (once per segment) through Lx[4][64] (P region)
    auto finishSeg = [&]() {
        #pragma unroll
        for (int t = 0; t < 4; ++t) {
            float lw = lsum[t];
            lw += __shfl_xor(lw, 16);
            lw += __shfl_xor(lw, 32);          // sum over quads: wave-partial l[q=16t+col]
            if (quad == 0) Lxf[wv * 64 + 16 * t + col] = lw;
        }
        __syncthreads();
        #pragma unroll
        for (int t = 0; t < 4; ++t)
            #pragma unroll
            for (int r = 0; r < 4; ++r) {
                int q = 16 * t + quad * 4 + r;
                lfull[t][r] = (Lxf[q] + Lxf[64 + q]) + (Lxf[128 + q] + Lxf[192 + q]);
            }
        __syncthreads();                        // Lx free before next seg's P writes
    };

    auto storeO = [&](int jq) {
        float* optr = O + ((size_t)b * S_LEN + jq * 64) * D_DIM;
        #pragma unroll
        for (int t = 0; t < 4; ++t)
            #pragma unroll
            for (int r = 0; r < 4; ++r) {
                float inv = 1.0f / lfull[t][r];
                #pragma unroll
                for (int dn = 0; dn < 2; ++dn)
                    optr[(16 * t + quad * 4 + r) * D_DIM + 32 * wv + 16 * dn + col] = oacc[t][dn][r] * inv;
            }
    };

    auto storePartial = [&]() {                 // heavy tile, slot = chunk c
        size_t slot = (size_t)((b * 16 + pi) * 2 + c);
        float* po = pO + slot * (64 * 128);
        float* pl = pL + slot * 64;
        #pragma unroll
        for (int t = 0; t < 4; ++t)
            #pragma unroll
            for (int r = 0; r < 4; ++r)
                #pragma unroll
                for (int dn = 0; dn < 2; ++dn)
                    po[(16 * t + quad * 4 + r) * 128 + 32 * wv + 16 * dn + col] = oacc[t][dn][r];
        if (wv == 0 && col == 0) {
            #pragma unroll
            for (int t = 0; t < 4; ++t)
                #pragma unroll
                for (int r = 0; r < 4; ++r)
                    pl[16 * t + quad * 4 + r] = lfull[t][r];
        }
    };

    if (c == 0) {
        runSeg(pi, 0, L);                       // light, complete
        finishSeg();
        storeO(pi);
        runSeg(qtH, 0, 17 - L);                 // heavy prefix
        finishSeg();
        storePartial();
    } else {
        runSeg(qtH, 17 - L, 16);                // heavy suffix incl. diagonal
        finishSeg();
        storePartial();
    }
}

// ---- nrm: heavy q-tiles only: O = (pO[slot0]+pO[slot1]) / (pL0+pL1) ----
__global__ void nrm_kernel(const float* __restrict__ pO, const float* __restrict__ pL,
                           float* __restrict__ O) {
    int gid  = blockIdx.x * 256 + threadIdx.x;   // 512 blocks -> 131072 threads
    int flat = gid * 16;                          // 16*16*64*128 = 2.097M f32
    int pr   = flat >> 13;                        // (b*16+pi)
    int rl   = (flat >> 7) & 63;
    int cc   = flat & 127;
    int b = pr >> 4, pi = pr & 15;
    const float* p0 = pO + ((size_t)pr * 2)     * 8192 + rl * 128 + cc;
    const float* p1 = pO + ((size_t)pr * 2 + 1) * 8192 + rl * 128 + cc;
    float inv = 1.0f / (pL[(pr * 2) * 64 + rl] + pL[(pr * 2 + 1) * 64 + rl]);
    float* op = O + ((size_t)b * S_LEN + (31 - pi) * 64 + rl) * D_DIM + cc;
    #pragma unroll
    for (int j = 0; j < 4; ++j) {
        f32x4 a = *(const f32x4*)(p0 + j * 4);
        f32x4 d = *(const f32x4*)(p1 + j * 4);
        f32x4 o;
        #pragma unroll
        for (int r = 0; r < 4; ++r) o[r] = (a[r] + d[r]) * inv;
        *(f32x4*)(op + j * 4) = o;
    }
}

extern "C" void kernel_launch(void* const* d_in, const int* in_sizes, int n_in,
                              void* d_out, int out_size, void* d_ws, size_t ws_size,
                              hipStream_t stream) {
    const float* Q = (const float*)d_in[0];
    const float* T = (const float*)d_in[1];
    const float* V = (const float*)d_in[2];
    float* O = (float*)d_out;

    // ws: Vt 8MB | Tb 8MB | pO 16.78MB | pL 128KB   (~33.7MB)
    unsigned char* ws = (unsigned char*)d_ws;
    __bf16* Vt = (__bf16*)ws;
    __bf16* Tb = (__bf16*)(ws + 8388608);
    float*  pO = (float*)(ws + 16777216);
    float*  pL = (float*)(ws + 16777216 + 16777216);

    prep_kernel<<<1024, 256, 0, stream>>>(V, T, Vt, Tb);
    fa_kernel<<<512, 256, 0, stream>>>(Q, Tb, Vt, O, pO, pL);
    nrm_kernel<<<512, 256, 0, stream>>>(pO, pL, O);
}